// Round 1
// baseline (350.456 us; speedup 1.0000x reference)
//
#include <hip/hip_runtime.h>

#define BB 4
#define CIN 256
#define CO 64
#define HW_ 4096

typedef __attribute__((ext_vector_type(8))) short short8;
typedef __attribute__((ext_vector_type(4))) float f32x4;

__device__ inline unsigned short f2bf(float f) {
  union { float f; unsigned u; } x; x.f = f;
  unsigned r = x.u + 0x7fffu + ((x.u >> 16) & 1u);  // RNE
  return (unsigned short)(r >> 16);
}

// ---------------------------------------------------------------------------
// K1: QKV projection (f32 VALU), writes qT/kT as [b][pos][64] bf16,
//     v as [b][64][pos] bf16.
// grid (64,4) block 256: block = (b, 64-pos tile). thread: d = tid&63,
// mgroup = tid>>6 owns 48 of the 192 stacked output channels.
// ---------------------------------------------------------------------------
__global__ __launch_bounds__(256) void qkv_kernel(
    const float* __restrict__ x,
    const float* __restrict__ wq, const float* __restrict__ bq,
    const float* __restrict__ wk, const float* __restrict__ bk,
    const float* __restrict__ wv, const float* __restrict__ bv,
    unsigned short* __restrict__ qT, unsigned short* __restrict__ kT,
    unsigned short* __restrict__ v)
{
  const int b = blockIdx.y;
  const int d0 = blockIdx.x * 64;
  const int tid = threadIdx.x;
  const int d = tid & 63;
  const int mg = tid >> 6;

  __shared__ float xs[32][64];     // [f][d] chunk
  __shared__ float wls[32][196];   // [f][m(192)+pad]  (reused as u16 transpose buf)

  float acc[48];
#pragma unroll
  for (int i = 0; i < 48; ++i) {
    int m = mg * 48 + i;
    const float* bb = (m < 64) ? bq : ((m < 128) ? bk : bv);
    acc[i] = bb[m & 63];
  }

  const float* xb = x + (size_t)b * CIN * HW_;

  for (int f0 = 0; f0 < CIN; f0 += 32) {
    __syncthreads();
    // stage x chunk [32 f][64 d]
#pragma unroll
    for (int i = 0; i < 2; ++i) {
      int lin = i * 256 + tid;            // float4 index
      int f = lin >> 4, c4 = lin & 15;
      reinterpret_cast<float4*>(&xs[0][0])[lin] =
          *reinterpret_cast<const float4*>(&xb[(size_t)(f0 + f) * HW_ + d0 + c4 * 4]);
    }
    // stage W^T chunk [32 f][192 m]
#pragma unroll
    for (int i = 0; i < 24; ++i) {
      int lin = i * 256 + tid;            // m-major: m = lin>>5, f = lin&31
      int m = lin >> 5, f = lin & 31;
      const float* wm = (m < 64) ? (wq + (size_t)m * CIN)
                       : ((m < 128) ? (wk + (size_t)(m - 64) * CIN)
                                    : (wv + (size_t)(m - 128) * CIN));
      wls[f][m] = wm[f0 + f];
    }
    __syncthreads();
#pragma unroll 4
    for (int f = 0; f < 32; ++f) {
      float xv = xs[f][d];
#pragma unroll
      for (int j = 0; j < 12; ++j) {
        float4 w4 = *reinterpret_cast<const float4*>(&wls[f][mg * 48 + j * 4]);
        acc[j * 4 + 0] = fmaf(w4.x, xv, acc[j * 4 + 0]);
        acc[j * 4 + 1] = fmaf(w4.y, xv, acc[j * 4 + 1]);
        acc[j * 4 + 2] = fmaf(w4.z, xv, acc[j * 4 + 2]);
        acc[j * 4 + 3] = fmaf(w4.w, xv, acc[j * 4 + 3]);
      }
    }
  }

  // epilogue: q,k through LDS transpose for coalesced [d][c] stores; v direct.
  __syncthreads();
  unsigned short* plds = reinterpret_cast<unsigned short*>(&wls[0][0]); // [64 d][132 u16]
#pragma unroll
  for (int i = 0; i < 48; i += 2) {
    int m = mg * 48 + i;
    if (m < 128) {
      unsigned pw = (unsigned)f2bf(acc[i]) | ((unsigned)f2bf(acc[i + 1]) << 16);
      *reinterpret_cast<unsigned*>(&plds[d * 132 + m]) = pw;
    } else {
      v[((size_t)b * CO + (m - 128)) * HW_ + d0 + d] = f2bf(acc[i]);
      v[((size_t)b * CO + (m - 127)) * HW_ + d0 + d] = f2bf(acc[i + 1]);
    }
  }
  __syncthreads();
  const size_t qbase = ((size_t)b * HW_ + d0) * 64;
#pragma unroll
  for (int i = 0; i < 8; ++i) {
    int lin = i * 256 + tid;              // u32 index: row = lin>>5, c2 = lin&31
    int dr = lin >> 5, c2 = lin & 31;
    unsigned qw = *reinterpret_cast<const unsigned*>(&plds[dr * 132 + c2 * 2]);
    unsigned kw = *reinterpret_cast<const unsigned*>(&plds[dr * 132 + 64 + c2 * 2]);
    *reinterpret_cast<unsigned*>(&qT[qbase + (size_t)dr * 64 + c2 * 2]) = qw;
    *reinterpret_cast<unsigned*>(&kT[qbase + (size_t)dr * 64 + c2 * 2]) = kw;
  }
}

// ---------------------------------------------------------------------------
// K2a: per-query-row softmax stats ml[d] = max_e S[d,e] + log sum_e exp(S-max).
// block = (b, 64 query rows); wave owns 16 rows. S^T computed via mfma(K,Q).
// ---------------------------------------------------------------------------
__global__ __launch_bounds__(256) void stats_kernel(
    const unsigned short* __restrict__ qT,
    const unsigned short* __restrict__ kT,
    float* __restrict__ ml)
{
  const int b = blockIdx.y;
  const int dt0 = blockIdx.x * 64;
  const int tid = threadIdx.x;
  const int wid = tid >> 6, lane = tid & 63;
  const int lq = lane & 15, quad = lane >> 4;

  __shared__ unsigned char kt_lds[8192];   // [64 e][64 c] bf16, xor-swizzled

  const size_t base = (size_t)b * HW_ * CO;
  const int d = dt0 + wid * 16 + lq;
  const short8 qf0 = *reinterpret_cast<const short8*>(&qT[base + (size_t)d * 64 + quad * 8]);
  const short8 qf1 = *reinterpret_cast<const short8*>(&qT[base + (size_t)d * 64 + 32 + quad * 8]);

  float m_run = -3.0e38f, l_run = 0.f;
  const char* kT_bytes = reinterpret_cast<const char*>(kT) + base * 2;

  for (int e0 = 0; e0 < HW_; e0 += 64) {
    float4 kreg[2];
#pragma unroll
    for (int i = 0; i < 2; ++i) {
      int L = (i * 256 + tid) * 16;
      int row = L >> 7, colb = L & 127;
      int scol = colb ^ ((row & 7) << 4);
      kreg[i] = *reinterpret_cast<const float4*>(kT_bytes + (size_t)e0 * 128 + row * 128 + scol);
    }
    __syncthreads();
#pragma unroll
    for (int i = 0; i < 2; ++i) {
      int L = (i * 256 + tid) * 16;
      *reinterpret_cast<float4*>(kt_lds + L) = kreg[i];
    }
    __syncthreads();

    const f32x4 zero = {0.f, 0.f, 0.f, 0.f};
    f32x4 sT[4];
#pragma unroll
    for (int mt = 0; mt < 4; ++mt) sT[mt] = zero;
#pragma unroll
    for (int s = 0; s < 2; ++s)
#pragma unroll
      for (int mt = 0; mt < 4; ++mt) {
        int row = mt * 16 + lq;
        int addr = (row * 128 + s * 64 + quad * 16) ^ ((row & 7) << 4);
        short8 af = *reinterpret_cast<const short8*>(kt_lds + addr);
        sT[mt] = __builtin_amdgcn_mfma_f32_16x16x32_bf16(af, s ? qf1 : qf0, sT[mt], 0, 0, 0);
      }

    float tmax = -3.0e38f;
#pragma unroll
    for (int mt = 0; mt < 4; ++mt)
#pragma unroll
      for (int r = 0; r < 4; ++r) tmax = fmaxf(tmax, sT[mt][r]);
    tmax = fmaxf(tmax, __shfl_xor(tmax, 16));
    tmax = fmaxf(tmax, __shfl_xor(tmax, 32));
    float m_new = fmaxf(m_run, tmax);
    float corr = __expf(m_run - m_new);
    float lsum = 0.f;
#pragma unroll
    for (int mt = 0; mt < 4; ++mt)
#pragma unroll
      for (int r = 0; r < 4; ++r) lsum += __expf(sT[mt][r] - m_new);
    lsum += __shfl_xor(lsum, 16);
    lsum += __shfl_xor(lsum, 32);
    l_run = l_run * corr + lsum;
    m_run = m_new;
  }
  if (quad == 0) ml[(size_t)b * HW_ + d] = m_run + __logf(l_run);
}

// ---------------------------------------------------------------------------
// K2b: o[c,e] = sum_d v[c,d] * exp(S[d,e] - ml[d]).
// block = (b, 64 output positions e); wave owns 16 e. Loop over all d tiles:
// recompute S^T tile via mfma(K_e, Q_d), exponentiate with exact stats,
// bridge to B-frag layout via per-wave LDS, MFMA-accumulate with V.
// ---------------------------------------------------------------------------
__global__ __launch_bounds__(256) void apply_kernel(
    const unsigned short* __restrict__ qT,
    const unsigned short* __restrict__ kT,
    const unsigned short* __restrict__ vv,
    const float* __restrict__ ml,
    float* __restrict__ O)
{
  const int b = blockIdx.y;
  const int et0 = blockIdx.x * 64;
  const int tid = threadIdx.x;
  const int wid = tid >> 6, lane = tid & 63;
  const int lq = lane & 15, quad = lane >> 4;

  __shared__ unsigned char q_lds[8192];        // [64 d][64 c] bf16, swizzled
  __shared__ unsigned char v_lds[8192];        // [64 c][64 d] bf16, swizzled
  __shared__ float ml_lds[64];
  __shared__ unsigned short p_lds[4][16][72];  // per-wave [16 e][64 d + pad]

  const size_t base = (size_t)b * HW_ * CO;
  const int e = et0 + wid * 16 + lq;
  const short8 kf0 = *reinterpret_cast<const short8*>(&kT[base + (size_t)e * 64 + quad * 8]);
  const short8 kf1 = *reinterpret_cast<const short8*>(&kT[base + (size_t)e * 64 + 32 + quad * 8]);

  const f32x4 zero = {0.f, 0.f, 0.f, 0.f};
  f32x4 Of[4];
#pragma unroll
  for (int ct = 0; ct < 4; ++ct) Of[ct] = zero;

  const char* qT_bytes = reinterpret_cast<const char*>(qT) + base * 2;
  const char* v_bytes = reinterpret_cast<const char*>(vv) + base * 2;

  for (int dt = 0; dt < HW_; dt += 64) {
    float4 qreg[2], vreg[2];
#pragma unroll
    for (int i = 0; i < 2; ++i) {
      int L = (i * 256 + tid) * 16;
      int row = L >> 7, colb = L & 127;
      int scol = colb ^ ((row & 7) << 4);
      qreg[i] = *reinterpret_cast<const float4*>(qT_bytes + (size_t)dt * 128 + row * 128 + scol);
      vreg[i] = *reinterpret_cast<const float4*>(v_bytes + (size_t)row * 8192 + dt * 2 + scol);
    }
    float mlv = 0.f;
    if (tid < 64) mlv = ml[(size_t)b * HW_ + dt + tid];
    __syncthreads();
#pragma unroll
    for (int i = 0; i < 2; ++i) {
      int L = (i * 256 + tid) * 16;
      *reinterpret_cast<float4*>(q_lds + L) = qreg[i];
      *reinterpret_cast<float4*>(v_lds + L) = vreg[i];
    }
    if (tid < 64) ml_lds[tid] = mlv;
    __syncthreads();

    // T[e_loc, d_loc] = S[d, e] for wave's 16 e x 64 d
    f32x4 T[4];
#pragma unroll
    for (int nt = 0; nt < 4; ++nt) T[nt] = zero;
#pragma unroll
    for (int s = 0; s < 2; ++s)
#pragma unroll
      for (int nt = 0; nt < 4; ++nt) {
        int row = nt * 16 + lq;
        int addr = (row * 128 + s * 64 + quad * 16) ^ ((row & 7) << 4);
        short8 qfr = *reinterpret_cast<const short8*>(q_lds + addr);
        T[nt] = __builtin_amdgcn_mfma_f32_16x16x32_bf16(s ? kf1 : kf0, qfr, T[nt], 0, 0, 0);
      }
    // P = exp(S - ml[d]) -> per-wave LDS [e_loc][d_loc] bf16
#pragma unroll
    for (int nt = 0; nt < 4; ++nt) {
      float mld = ml_lds[nt * 16 + lq];
#pragma unroll
      for (int r = 0; r < 4; ++r) {
        float p = __expf(T[nt][r] - mld);
        p_lds[wid][quad * 4 + r][nt * 16 + lq] = f2bf(p);
      }
    }
    // PV: O[c, e] += V[c, d] * P[d, e]   (same-wave DS pipe is in-order)
#pragma unroll
    for (int s = 0; s < 2; ++s) {
      short8 pf = *reinterpret_cast<const short8*>(
          reinterpret_cast<const unsigned char*>(&p_lds[wid][0][0]) + lq * 144 + s * 64 + quad * 16);
#pragma unroll
      for (int ct = 0; ct < 4; ++ct) {
        int row = ct * 16 + lq;
        int addr = (row * 128 + s * 64 + quad * 16) ^ ((row & 7) << 4);
        short8 vf = *reinterpret_cast<const short8*>(v_lds + addr);
        Of[ct] = __builtin_amdgcn_mfma_f32_16x16x32_bf16(vf, pf, Of[ct], 0, 0, 0);
      }
    }
  }
#pragma unroll
  for (int ct = 0; ct < 4; ++ct)
#pragma unroll
    for (int r = 0; r < 4; ++r)
      O[((size_t)b * CO + ct * 16 + quad * 4 + r) * HW_ + e] = Of[ct][r];
}

// ---------------------------------------------------------------------------
// K3: out[f, d] = sum_c wo[f, c] * O[c, d] + bo[f]   (f32 VALU)
// ---------------------------------------------------------------------------
__global__ __launch_bounds__(256) void outproj_kernel(
    const float* __restrict__ O, const float* __restrict__ wo,
    const float* __restrict__ bo, float* __restrict__ out)
{
  const int b = blockIdx.z;
  const int f0 = blockIdx.y * 8;
  const int d = blockIdx.x * 256 + threadIdx.x;
  float acc[8];
#pragma unroll
  for (int j = 0; j < 8; ++j) acc[j] = bo[f0 + j];
  const float* Ob = O + (size_t)b * CO * HW_;
#pragma unroll 4
  for (int c = 0; c < CO; ++c) {
    float ov = Ob[(size_t)c * HW_ + d];
#pragma unroll
    for (int j = 0; j < 8; ++j)
      acc[j] = fmaf(wo[(size_t)(f0 + j) * CO + c], ov, acc[j]);
  }
#pragma unroll
  for (int j = 0; j < 8; ++j)
    out[((size_t)b * CIN + f0 + j) * HW_ + d] = acc[j];
}

extern "C" void kernel_launch(void* const* d_in, const int* in_sizes, int n_in,
                              void* d_out, int out_size, void* d_ws, size_t ws_size,
                              hipStream_t stream) {
  const float* x  = (const float*)d_in[0];
  const float* wq = (const float*)d_in[1];
  const float* bq = (const float*)d_in[2];
  const float* wk = (const float*)d_in[3];
  const float* bk = (const float*)d_in[4];
  const float* wv = (const float*)d_in[5];
  const float* bv = (const float*)d_in[6];
  const float* wo = (const float*)d_in[7];
  const float* bo = (const float*)d_in[8];
  float* out = (float*)d_out;

  char* ws = (char*)d_ws;
  unsigned short* qT = (unsigned short*)(ws);                 // 2 MB  [b][4096][64] bf16
  unsigned short* kT = (unsigned short*)(ws + (2u << 20));    // 2 MB  [b][4096][64] bf16
  unsigned short* v  = (unsigned short*)(ws + (4u << 20));    // 2 MB  [b][64][4096] bf16
  float* O           = (float*)(ws + (6u << 20));             // 4 MB  [b][64][4096] f32
  float* ml          = (float*)(ws + (10u << 20));            // 64 KB [b][4096] f32

  qkv_kernel<<<dim3(64, 4), 256, 0, stream>>>(x, wq, bq, wk, bk, wv, bv, qT, kT, v);
  stats_kernel<<<dim3(64, 4), 256, 0, stream>>>(qT, kT, ml);
  apply_kernel<<<dim3(64, 4), 256, 0, stream>>>(qT, kT, v, ml, O);
  outproj_kernel<<<dim3(16, 32, 4), 256, 0, stream>>>(O, wo, bo, out);
}

// Round 2
// 224.947 us; speedup vs baseline: 1.5579x; 1.5579x over previous
//
#include <hip/hip_runtime.h>

#define BB 4
#define CIN 256
#define CO 64
#define HW_ 4096

typedef __attribute__((ext_vector_type(8))) short short8;
typedef __attribute__((ext_vector_type(4))) float f32x4;

__device__ inline unsigned short f2bf(float f) {
  union { float f; unsigned u; } x; x.f = f;
  unsigned r = x.u + 0x7fffu + ((x.u >> 16) & 1u);  // RNE
  return (unsigned short)(r >> 16);
}
__device__ inline float bf2f(unsigned short h) {
  union { unsigned u; float f; } x; x.u = ((unsigned)h) << 16;
  return x.f;
}

// ---------------------------------------------------------------------------
// K1: QKV projection as MFMA GEMM. One block = one of {q,k,v} x 64-pos chunk.
// W panel [64 m][256 k] staged once in LDS (bf16, XOR-swizzled). X columns
// loaded per-lane from global in B-fragment layout, split hi/lo bf16 for
// f32-level accuracy. D written as qT/kT [b][pos][64] or v [b][64][pos].
// ---------------------------------------------------------------------------
__global__ __launch_bounds__(256, 3) void qkv_kernel(
    const float* __restrict__ x,
    const float* __restrict__ wq, const float* __restrict__ bq,
    const float* __restrict__ wk, const float* __restrict__ bk,
    const float* __restrict__ wv, const float* __restrict__ bv,
    unsigned short* __restrict__ qT, unsigned short* __restrict__ kT,
    unsigned short* __restrict__ v)
{
  const int b = blockIdx.z;
  const int which = blockIdx.y;       // 0=q, 1=k, 2=v
  const int n0 = blockIdx.x * 64;     // position base
  const int tid = threadIdx.x;
  const int w = tid >> 6, lane = tid & 63;
  const int lq = lane & 15, quad = lane >> 4;

  const float* W  = (which == 0) ? wq : (which == 1) ? wk : wv;
  const float* Bb = (which == 0) ? bq : (which == 1) ? bk : bv;

  __shared__ unsigned short w_lds[64 * 256];   // 32 KB, [m][k] bf16 swizzled
  unsigned char* wbytes = reinterpret_cast<unsigned char*>(w_lds);

  // stage W panel: 16384 f32 -> bf16, coalesced float4 loads
#pragma unroll
  for (int i = 0; i < 16; ++i) {
    int L = i * 256 + tid;            // float4 idx: row = L>>6, col4 = L&63
    int row = L >> 6, col4 = L & 63;
    float4 w4 = *reinterpret_cast<const float4*>(&W[row * 256 + col4 * 4]);
    ushort4 p;
    p.x = f2bf(w4.x); p.y = f2bf(w4.y); p.z = f2bf(w4.z); p.w = f2bf(w4.w);
    int addr = (row * 512 + col4 * 8) ^ ((row & 7) << 4);
    *reinterpret_cast<ushort4*>(wbytes + addr) = p;
  }
  __syncthreads();

  const int n = n0 + w * 16 + lq;     // this lane's position column
  const float* xb = x + (size_t)b * CIN * HW_ + n;

  const f32x4 zero = {0.f, 0.f, 0.f, 0.f};
  f32x4 acc[4];
#pragma unroll
  for (int mt = 0; mt < 4; ++mt) acc[mt] = zero;

  for (int ks = 0; ks < 8; ++ks) {
    // B fragment: X[k0 + quad*8 + j][n], j=0..7, split hi/lo bf16
    float xv[8];
#pragma unroll
    for (int j = 0; j < 8; ++j)
      xv[j] = xb[(size_t)(ks * 32 + quad * 8 + j) * HW_];
    short8 bhi, blo;
#pragma unroll
    for (int j = 0; j < 8; ++j) {
      unsigned short h = f2bf(xv[j]);
      bhi[j] = (short)h;
      blo[j] = (short)f2bf(xv[j] - bf2f(h));
    }
    // A fragments from LDS + MFMA
#pragma unroll
    for (int mt = 0; mt < 4; ++mt) {
      int addr = ((mt * 16 + lq) * 512 + ks * 64 + quad * 16) ^ ((lq & 7) << 4);
      short8 af = *reinterpret_cast<const short8*>(wbytes + addr);
      acc[mt] = __builtin_amdgcn_mfma_f32_16x16x32_bf16(af, bhi, acc[mt], 0, 0, 0);
      acc[mt] = __builtin_amdgcn_mfma_f32_16x16x32_bf16(af, blo, acc[mt], 0, 0, 0);
    }
  }

  // epilogue: bias + store
  float4 bias4[4];
#pragma unroll
  for (int mt = 0; mt < 4; ++mt)
    bias4[mt] = *reinterpret_cast<const float4*>(&Bb[mt * 16 + quad * 4]);

  if (which < 2) {
    unsigned short* outp = ((which == 0) ? qT : kT) + ((size_t)b * HW_ + n) * 64;
#pragma unroll
    for (int mt = 0; mt < 4; ++mt) {
      ushort4 p;
      p.x = f2bf(acc[mt][0] + bias4[mt].x);
      p.y = f2bf(acc[mt][1] + bias4[mt].y);
      p.z = f2bf(acc[mt][2] + bias4[mt].z);
      p.w = f2bf(acc[mt][3] + bias4[mt].w);
      *reinterpret_cast<ushort4*>(&outp[mt * 16 + quad * 4]) = p;
    }
  } else {
#pragma unroll
    for (int mt = 0; mt < 4; ++mt) {
      float bb[4] = {bias4[mt].x, bias4[mt].y, bias4[mt].z, bias4[mt].w};
#pragma unroll
      for (int r = 0; r < 4; ++r)
        v[((size_t)b * CO + mt * 16 + quad * 4 + r) * HW_ + n] = f2bf(acc[mt][r] + bb[r]);
    }
  }
}

// ---------------------------------------------------------------------------
// K2a: per-query-row softmax stats ml[d] = max_e S[d,e] + log sum_e exp(S-max).
// block = (b, 64 query rows); wave owns 16 rows. S^T computed via mfma(K,Q).
// ---------------------------------------------------------------------------
__global__ __launch_bounds__(256) void stats_kernel(
    const unsigned short* __restrict__ qT,
    const unsigned short* __restrict__ kT,
    float* __restrict__ ml)
{
  const int b = blockIdx.y;
  const int dt0 = blockIdx.x * 64;
  const int tid = threadIdx.x;
  const int wid = tid >> 6, lane = tid & 63;
  const int lq = lane & 15, quad = lane >> 4;

  __shared__ unsigned char kt_lds[8192];   // [64 e][64 c] bf16, xor-swizzled

  const size_t base = (size_t)b * HW_ * CO;
  const int d = dt0 + wid * 16 + lq;
  const short8 qf0 = *reinterpret_cast<const short8*>(&qT[base + (size_t)d * 64 + quad * 8]);
  const short8 qf1 = *reinterpret_cast<const short8*>(&qT[base + (size_t)d * 64 + 32 + quad * 8]);

  float m_run = -3.0e38f, l_run = 0.f;
  const char* kT_bytes = reinterpret_cast<const char*>(kT) + base * 2;

  for (int e0 = 0; e0 < HW_; e0 += 64) {
    float4 kreg[2];
#pragma unroll
    for (int i = 0; i < 2; ++i) {
      int L = (i * 256 + tid) * 16;
      int row = L >> 7, colb = L & 127;
      int scol = colb ^ ((row & 7) << 4);
      kreg[i] = *reinterpret_cast<const float4*>(kT_bytes + (size_t)e0 * 128 + row * 128 + scol);
    }
    __syncthreads();
#pragma unroll
    for (int i = 0; i < 2; ++i) {
      int L = (i * 256 + tid) * 16;
      *reinterpret_cast<float4*>(kt_lds + L) = kreg[i];
    }
    __syncthreads();

    const f32x4 zero = {0.f, 0.f, 0.f, 0.f};
    f32x4 sT[4];
#pragma unroll
    for (int mt = 0; mt < 4; ++mt) sT[mt] = zero;
#pragma unroll
    for (int s = 0; s < 2; ++s)
#pragma unroll
      for (int mt = 0; mt < 4; ++mt) {
        int row = mt * 16 + lq;
        int addr = (row * 128 + s * 64 + quad * 16) ^ ((row & 7) << 4);
        short8 af = *reinterpret_cast<const short8*>(kt_lds + addr);
        sT[mt] = __builtin_amdgcn_mfma_f32_16x16x32_bf16(af, s ? qf1 : qf0, sT[mt], 0, 0, 0);
      }

    float tmax = -3.0e38f;
#pragma unroll
    for (int mt = 0; mt < 4; ++mt)
#pragma unroll
      for (int r = 0; r < 4; ++r) tmax = fmaxf(tmax, sT[mt][r]);
    tmax = fmaxf(tmax, __shfl_xor(tmax, 16));
    tmax = fmaxf(tmax, __shfl_xor(tmax, 32));
    float m_new = fmaxf(m_run, tmax);
    float corr = __expf(m_run - m_new);
    float lsum = 0.f;
#pragma unroll
    for (int mt = 0; mt < 4; ++mt)
#pragma unroll
      for (int r = 0; r < 4; ++r) lsum += __expf(sT[mt][r] - m_new);
    lsum += __shfl_xor(lsum, 16);
    lsum += __shfl_xor(lsum, 32);
    l_run = l_run * corr + lsum;
    m_run = m_new;
  }
  if (quad == 0) ml[(size_t)b * HW_ + d] = m_run + __logf(l_run);
}

// ---------------------------------------------------------------------------
// K2b: o[c,e] = sum_d v[c,d] * exp(S[d,e] - ml[d]).
// ---------------------------------------------------------------------------
__global__ __launch_bounds__(256) void apply_kernel(
    const unsigned short* __restrict__ qT,
    const unsigned short* __restrict__ kT,
    const unsigned short* __restrict__ vv,
    const float* __restrict__ ml,
    float* __restrict__ O)
{
  const int b = blockIdx.y;
  const int et0 = blockIdx.x * 64;
  const int tid = threadIdx.x;
  const int wid = tid >> 6, lane = tid & 63;
  const int lq = lane & 15, quad = lane >> 4;

  __shared__ unsigned char q_lds[8192];        // [64 d][64 c] bf16, swizzled
  __shared__ unsigned char v_lds[8192];        // [64 c][64 d] bf16, swizzled
  __shared__ float ml_lds[64];
  __shared__ unsigned short p_lds[4][16][72];  // per-wave [16 e][64 d + pad]

  const size_t base = (size_t)b * HW_ * CO;
  const int e = et0 + wid * 16 + lq;
  const short8 kf0 = *reinterpret_cast<const short8*>(&kT[base + (size_t)e * 64 + quad * 8]);
  const short8 kf1 = *reinterpret_cast<const short8*>(&kT[base + (size_t)e * 64 + 32 + quad * 8]);

  const f32x4 zero = {0.f, 0.f, 0.f, 0.f};
  f32x4 Of[4];
#pragma unroll
  for (int ct = 0; ct < 4; ++ct) Of[ct] = zero;

  const char* qT_bytes = reinterpret_cast<const char*>(qT) + base * 2;
  const char* v_bytes = reinterpret_cast<const char*>(vv) + base * 2;

  for (int dt = 0; dt < HW_; dt += 64) {
    float4 qreg[2], vreg[2];
#pragma unroll
    for (int i = 0; i < 2; ++i) {
      int L = (i * 256 + tid) * 16;
      int row = L >> 7, colb = L & 127;
      int scol = colb ^ ((row & 7) << 4);
      qreg[i] = *reinterpret_cast<const float4*>(qT_bytes + (size_t)dt * 128 + row * 128 + scol);
      vreg[i] = *reinterpret_cast<const float4*>(v_bytes + (size_t)row * 8192 + dt * 2 + scol);
    }
    float mlv = 0.f;
    if (tid < 64) mlv = ml[(size_t)b * HW_ + dt + tid];
    __syncthreads();
#pragma unroll
    for (int i = 0; i < 2; ++i) {
      int L = (i * 256 + tid) * 16;
      *reinterpret_cast<float4*>(q_lds + L) = qreg[i];
      *reinterpret_cast<float4*>(v_lds + L) = vreg[i];
    }
    if (tid < 64) ml_lds[tid] = mlv;
    __syncthreads();

    // T[e_loc, d_loc] = S[d, e] for wave's 16 e x 64 d
    f32x4 T[4];
#pragma unroll
    for (int nt = 0; nt < 4; ++nt) T[nt] = zero;
#pragma unroll
    for (int s = 0; s < 2; ++s)
#pragma unroll
      for (int nt = 0; nt < 4; ++nt) {
        int row = nt * 16 + lq;
        int addr = (row * 128 + s * 64 + quad * 16) ^ ((row & 7) << 4);
        short8 qfr = *reinterpret_cast<const short8*>(q_lds + addr);
        T[nt] = __builtin_amdgcn_mfma_f32_16x16x32_bf16(s ? kf1 : kf0, qfr, T[nt], 0, 0, 0);
      }
    // P = exp(S - ml[d]) -> per-wave LDS [e_loc][d_loc] bf16
#pragma unroll
    for (int nt = 0; nt < 4; ++nt) {
      float mld = ml_lds[nt * 16 + lq];
#pragma unroll
      for (int r = 0; r < 4; ++r) {
        float p = __expf(T[nt][r] - mld);
        p_lds[wid][quad * 4 + r][nt * 16 + lq] = f2bf(p);
      }
    }
    // PV: O[c, e] += V[c, d] * P[d, e]
#pragma unroll
    for (int s = 0; s < 2; ++s) {
      short8 pf = *reinterpret_cast<const short8*>(
          reinterpret_cast<const unsigned char*>(&p_lds[wid][0][0]) + lq * 144 + s * 64 + quad * 16);
#pragma unroll
      for (int ct = 0; ct < 4; ++ct) {
        int row = ct * 16 + lq;
        int addr = (row * 128 + s * 64 + quad * 16) ^ ((row & 7) << 4);
        short8 vf = *reinterpret_cast<const short8*>(v_lds + addr);
        Of[ct] = __builtin_amdgcn_mfma_f32_16x16x32_bf16(vf, pf, Of[ct], 0, 0, 0);
      }
    }
  }
#pragma unroll
  for (int ct = 0; ct < 4; ++ct)
#pragma unroll
    for (int r = 0; r < 4; ++r)
      O[((size_t)b * CO + ct * 16 + quad * 4 + r) * HW_ + e] = Of[ct][r];
}

// ---------------------------------------------------------------------------
// K3: out[f, d] = sum_c wo[f, c] * O[c, d] + bo[f]   (f32 VALU)
// ---------------------------------------------------------------------------
__global__ __launch_bounds__(256) void outproj_kernel(
    const float* __restrict__ O, const float* __restrict__ wo,
    const float* __restrict__ bo, float* __restrict__ out)
{
  const int b = blockIdx.z;
  const int f0 = blockIdx.y * 8;
  const int d = blockIdx.x * 256 + threadIdx.x;
  float acc[8];
#pragma unroll
  for (int j = 0; j < 8; ++j) acc[j] = bo[f0 + j];
  const float* Ob = O + (size_t)b * CO * HW_;
#pragma unroll 4
  for (int c = 0; c < CO; ++c) {
    float ov = Ob[(size_t)c * HW_ + d];
#pragma unroll
    for (int j = 0; j < 8; ++j)
      acc[j] = fmaf(wo[(size_t)(f0 + j) * CO + c], ov, acc[j]);
  }
#pragma unroll
  for (int j = 0; j < 8; ++j)
    out[((size_t)b * CIN + f0 + j) * HW_ + d] = acc[j];
}

extern "C" void kernel_launch(void* const* d_in, const int* in_sizes, int n_in,
                              void* d_out, int out_size, void* d_ws, size_t ws_size,
                              hipStream_t stream) {
  const float* x  = (const float*)d_in[0];
  const float* wq = (const float*)d_in[1];
  const float* bq = (const float*)d_in[2];
  const float* wk = (const float*)d_in[3];
  const float* bk = (const float*)d_in[4];
  const float* wv = (const float*)d_in[5];
  const float* bv = (const float*)d_in[6];
  const float* wo = (const float*)d_in[7];
  const float* bo = (const float*)d_in[8];
  float* out = (float*)d_out;

  char* ws = (char*)d_ws;
  unsigned short* qT = (unsigned short*)(ws);                 // 2 MB  [b][4096][64] bf16
  unsigned short* kT = (unsigned short*)(ws + (2u << 20));    // 2 MB  [b][4096][64] bf16
  unsigned short* v  = (unsigned short*)(ws + (4u << 20));    // 2 MB  [b][64][4096] bf16
  float* O           = (float*)(ws + (6u << 20));             // 4 MB  [b][64][4096] f32
  float* ml          = (float*)(ws + (10u << 20));            // 64 KB [b][4096] f32

  qkv_kernel<<<dim3(64, 3, 4), 256, 0, stream>>>(x, wq, bq, wk, bk, wv, bv, qT, kT, v);
  stats_kernel<<<dim3(64, 4), 256, 0, stream>>>(qT, kT, ml);
  apply_kernel<<<dim3(64, 4), 256, 0, stream>>>(qT, kT, v, ml, O);
  outproj_kernel<<<dim3(16, 32, 4), 256, 0, stream>>>(O, wo, bo, out);
}

// Round 3
// 162.972 us; speedup vs baseline: 2.1504x; 1.3803x over previous
//
#include <hip/hip_runtime.h>

#define BB 4
#define CIN 256
#define CO 64
#define HW_ 4096
#define NSPLIT 4
#define DCHUNK (HW_ / NSPLIT)

typedef __attribute__((ext_vector_type(8))) short short8;
typedef __attribute__((ext_vector_type(4))) float f32x4;

__device__ inline unsigned short f2bf(float f) {
  union { float f; unsigned u; } x; x.f = f;
  unsigned r = x.u + 0x7fffu + ((x.u >> 16) & 1u);  // RNE
  return (unsigned short)(r >> 16);
}
__device__ inline float bf2f(unsigned short h) {
  union { unsigned u; float f; } x; x.u = ((unsigned)h) << 16;
  return x.f;
}

// ---------------------------------------------------------------------------
// K1: QKV projection as MFMA GEMM. One block = one of {q,k,v} x 64-pos chunk.
// ---------------------------------------------------------------------------
__global__ __launch_bounds__(256, 3) void qkv_kernel(
    const float* __restrict__ x,
    const float* __restrict__ wq, const float* __restrict__ bq,
    const float* __restrict__ wk, const float* __restrict__ bk,
    const float* __restrict__ wv, const float* __restrict__ bv,
    unsigned short* __restrict__ qT, unsigned short* __restrict__ kT,
    unsigned short* __restrict__ v)
{
  const int b = blockIdx.z;
  const int which = blockIdx.y;       // 0=q, 1=k, 2=v
  const int n0 = blockIdx.x * 64;     // position base
  const int tid = threadIdx.x;
  const int w = tid >> 6, lane = tid & 63;
  const int lq = lane & 15, quad = lane >> 4;

  const float* W  = (which == 0) ? wq : (which == 1) ? wk : wv;
  const float* Bb = (which == 0) ? bq : (which == 1) ? bk : bv;

  __shared__ unsigned short w_lds[64 * 256];   // 32 KB, [m][k] bf16 swizzled
  unsigned char* wbytes = reinterpret_cast<unsigned char*>(w_lds);

#pragma unroll
  for (int i = 0; i < 16; ++i) {
    int L = i * 256 + tid;
    int row = L >> 6, col4 = L & 63;
    float4 w4 = *reinterpret_cast<const float4*>(&W[row * 256 + col4 * 4]);
    ushort4 p;
    p.x = f2bf(w4.x); p.y = f2bf(w4.y); p.z = f2bf(w4.z); p.w = f2bf(w4.w);
    int addr = (row * 512 + col4 * 8) ^ ((row & 7) << 4);
    *reinterpret_cast<ushort4*>(wbytes + addr) = p;
  }
  __syncthreads();

  const int n = n0 + w * 16 + lq;
  const float* xb = x + (size_t)b * CIN * HW_ + n;

  const f32x4 zero = {0.f, 0.f, 0.f, 0.f};
  f32x4 acc[4];
#pragma unroll
  for (int mt = 0; mt < 4; ++mt) acc[mt] = zero;

  for (int ks = 0; ks < 8; ++ks) {
    float xv[8];
#pragma unroll
    for (int j = 0; j < 8; ++j)
      xv[j] = xb[(size_t)(ks * 32 + quad * 8 + j) * HW_];
    short8 bhi, blo;
#pragma unroll
    for (int j = 0; j < 8; ++j) {
      unsigned short h = f2bf(xv[j]);
      bhi[j] = (short)h;
      blo[j] = (short)f2bf(xv[j] - bf2f(h));
    }
#pragma unroll
    for (int mt = 0; mt < 4; ++mt) {
      int addr = ((mt * 16 + lq) * 512 + ks * 64 + quad * 16) ^ ((lq & 7) << 4);
      short8 af = *reinterpret_cast<const short8*>(wbytes + addr);
      acc[mt] = __builtin_amdgcn_mfma_f32_16x16x32_bf16(af, bhi, acc[mt], 0, 0, 0);
      acc[mt] = __builtin_amdgcn_mfma_f32_16x16x32_bf16(af, blo, acc[mt], 0, 0, 0);
    }
  }

  float4 bias4[4];
#pragma unroll
  for (int mt = 0; mt < 4; ++mt)
    bias4[mt] = *reinterpret_cast<const float4*>(&Bb[mt * 16 + quad * 4]);

  if (which < 2) {
    unsigned short* outp = ((which == 0) ? qT : kT) + ((size_t)b * HW_ + n) * 64;
#pragma unroll
    for (int mt = 0; mt < 4; ++mt) {
      ushort4 p;
      p.x = f2bf(acc[mt][0] + bias4[mt].x);
      p.y = f2bf(acc[mt][1] + bias4[mt].y);
      p.z = f2bf(acc[mt][2] + bias4[mt].z);
      p.w = f2bf(acc[mt][3] + bias4[mt].w);
      *reinterpret_cast<ushort4*>(&outp[mt * 16 + quad * 4]) = p;
    }
  } else {
#pragma unroll
    for (int mt = 0; mt < 4; ++mt) {
      float bb[4] = {bias4[mt].x, bias4[mt].y, bias4[mt].z, bias4[mt].w};
#pragma unroll
      for (int r = 0; r < 4; ++r)
        v[((size_t)b * CO + mt * 16 + quad * 4 + r) * HW_ + n] = f2bf(acc[mt][r] + bb[r]);
    }
  }
}

// ---------------------------------------------------------------------------
// K2a: partial softmax stats over an e-chunk. block = (d-tile, e-split, b).
// Writes (m, l) per (d, split); exact merge in combine_kernel.
// ---------------------------------------------------------------------------
__global__ __launch_bounds__(256, 4) void stats_kernel(
    const unsigned short* __restrict__ qT,
    const unsigned short* __restrict__ kT,
    float2* __restrict__ parts)
{
  const int b = blockIdx.z;
  const int split = blockIdx.y;
  const int dt0 = blockIdx.x * 64;
  const int tid = threadIdx.x;
  const int wid = tid >> 6, lane = tid & 63;
  const int lq = lane & 15, quad = lane >> 4;

  __shared__ unsigned char kt_lds[8192];   // [64 e][64 c] bf16, xor-swizzled

  const size_t base = (size_t)b * HW_ * CO;
  const int d = dt0 + wid * 16 + lq;
  const short8 qf0 = *reinterpret_cast<const short8*>(&qT[base + (size_t)d * 64 + quad * 8]);
  const short8 qf1 = *reinterpret_cast<const short8*>(&qT[base + (size_t)d * 64 + 32 + quad * 8]);

  float m_run = -3.0e38f, l_run = 0.f;
  const char* kT_bytes = reinterpret_cast<const char*>(kT) + base * 2;

  const int e_beg = split * DCHUNK;
  for (int e0 = e_beg; e0 < e_beg + DCHUNK; e0 += 64) {
    float4 kreg[2];
#pragma unroll
    for (int i = 0; i < 2; ++i) {
      int L = (i * 256 + tid) * 16;
      int row = L >> 7, colb = L & 127;
      int scol = colb ^ ((row & 7) << 4);
      kreg[i] = *reinterpret_cast<const float4*>(kT_bytes + (size_t)e0 * 128 + row * 128 + scol);
    }
    __syncthreads();
#pragma unroll
    for (int i = 0; i < 2; ++i) {
      int L = (i * 256 + tid) * 16;
      *reinterpret_cast<float4*>(kt_lds + L) = kreg[i];
    }
    __syncthreads();

    const f32x4 zero = {0.f, 0.f, 0.f, 0.f};
    f32x4 sT[4];
#pragma unroll
    for (int mt = 0; mt < 4; ++mt) sT[mt] = zero;
#pragma unroll
    for (int s = 0; s < 2; ++s)
#pragma unroll
      for (int mt = 0; mt < 4; ++mt) {
        int row = mt * 16 + lq;
        int addr = (row * 128 + s * 64 + quad * 16) ^ ((row & 7) << 4);
        short8 af = *reinterpret_cast<const short8*>(kt_lds + addr);
        sT[mt] = __builtin_amdgcn_mfma_f32_16x16x32_bf16(af, s ? qf1 : qf0, sT[mt], 0, 0, 0);
      }

    float tmax = -3.0e38f;
#pragma unroll
    for (int mt = 0; mt < 4; ++mt)
#pragma unroll
      for (int r = 0; r < 4; ++r) tmax = fmaxf(tmax, sT[mt][r]);
    tmax = fmaxf(tmax, __shfl_xor(tmax, 16));
    tmax = fmaxf(tmax, __shfl_xor(tmax, 32));
    float m_new = fmaxf(m_run, tmax);
    float corr = __expf(m_run - m_new);
    float lsum = 0.f;
#pragma unroll
    for (int mt = 0; mt < 4; ++mt)
#pragma unroll
      for (int r = 0; r < 4; ++r) lsum += __expf(sT[mt][r] - m_new);
    lsum += __shfl_xor(lsum, 16);
    lsum += __shfl_xor(lsum, 32);
    l_run = l_run * corr + lsum;
    m_run = m_new;
  }
  if (quad == 0)
    parts[((size_t)b * HW_ + d) * NSPLIT + split] = make_float2(m_run, l_run);
}

// ---------------------------------------------------------------------------
// K2b: merge per-split stats -> ml[d] = M + log sum l_i exp(m_i - M). Exact.
// ---------------------------------------------------------------------------
__global__ __launch_bounds__(256) void combine_kernel(
    const float2* __restrict__ parts, float* __restrict__ ml)
{
  const int r = blockIdx.x * 256 + threadIdx.x;
  float2 p[NSPLIT];
#pragma unroll
  for (int i = 0; i < NSPLIT; ++i) p[i] = parts[(size_t)r * NSPLIT + i];
  float M = p[0].x;
#pragma unroll
  for (int i = 1; i < NSPLIT; ++i) M = fmaxf(M, p[i].x);
  float L = 0.f;
#pragma unroll
  for (int i = 0; i < NSPLIT; ++i) L += p[i].y * __expf(p[i].x - M);
  ml[r] = M + __logf(L);
}

// ---------------------------------------------------------------------------
// K3: partial o[c,e] over a d-chunk. block = (e-tile, d-split, b).
// ---------------------------------------------------------------------------
__global__ __launch_bounds__(256, 4) void apply_kernel(
    const unsigned short* __restrict__ qT,
    const unsigned short* __restrict__ kT,
    const unsigned short* __restrict__ vv,
    const float* __restrict__ ml,
    float* __restrict__ Opart)
{
  const int b = blockIdx.z;
  const int split = blockIdx.y;
  const int et0 = blockIdx.x * 64;
  const int tid = threadIdx.x;
  const int wid = tid >> 6, lane = tid & 63;
  const int lq = lane & 15, quad = lane >> 4;

  __shared__ unsigned char q_lds[8192];        // [64 d][64 c] bf16, swizzled
  __shared__ unsigned char v_lds[8192];        // [64 c][64 d] bf16, swizzled
  __shared__ float ml_lds[64];
  __shared__ unsigned short p_lds[4][16][72];  // per-wave [16 e][64 d + pad]

  const size_t base = (size_t)b * HW_ * CO;
  const int e = et0 + wid * 16 + lq;
  const short8 kf0 = *reinterpret_cast<const short8*>(&kT[base + (size_t)e * 64 + quad * 8]);
  const short8 kf1 = *reinterpret_cast<const short8*>(&kT[base + (size_t)e * 64 + 32 + quad * 8]);

  const f32x4 zero = {0.f, 0.f, 0.f, 0.f};
  f32x4 Of[4];
#pragma unroll
  for (int ct = 0; ct < 4; ++ct) Of[ct] = zero;

  const char* qT_bytes = reinterpret_cast<const char*>(qT) + base * 2;
  const char* v_bytes = reinterpret_cast<const char*>(vv) + base * 2;

  const int d_beg = split * DCHUNK;
  for (int dt = d_beg; dt < d_beg + DCHUNK; dt += 64) {
    float4 qreg[2], vreg[2];
#pragma unroll
    for (int i = 0; i < 2; ++i) {
      int L = (i * 256 + tid) * 16;
      int row = L >> 7, colb = L & 127;
      int scol = colb ^ ((row & 7) << 4);
      qreg[i] = *reinterpret_cast<const float4*>(qT_bytes + (size_t)dt * 128 + row * 128 + scol);
      vreg[i] = *reinterpret_cast<const float4*>(v_bytes + (size_t)row * 8192 + dt * 2 + scol);
    }
    float mlv = 0.f;
    if (tid < 64) mlv = ml[(size_t)b * HW_ + dt + tid];
    __syncthreads();
#pragma unroll
    for (int i = 0; i < 2; ++i) {
      int L = (i * 256 + tid) * 16;
      *reinterpret_cast<float4*>(q_lds + L) = qreg[i];
      *reinterpret_cast<float4*>(v_lds + L) = vreg[i];
    }
    if (tid < 64) ml_lds[tid] = mlv;
    __syncthreads();

    // T[e_loc, d_loc] = S[d, e] for wave's 16 e x 64 d
    f32x4 T[4];
#pragma unroll
    for (int nt = 0; nt < 4; ++nt) T[nt] = zero;
#pragma unroll
    for (int s = 0; s < 2; ++s)
#pragma unroll
      for (int nt = 0; nt < 4; ++nt) {
        int row = nt * 16 + lq;
        int addr = (row * 128 + s * 64 + quad * 16) ^ ((row & 7) << 4);
        short8 qfr = *reinterpret_cast<const short8*>(q_lds + addr);
        T[nt] = __builtin_amdgcn_mfma_f32_16x16x32_bf16(s ? kf1 : kf0, qfr, T[nt], 0, 0, 0);
      }
    // P = exp(S - ml[d]) -> per-wave LDS [e_loc][d_loc] bf16
#pragma unroll
    for (int nt = 0; nt < 4; ++nt) {
      float mld = ml_lds[nt * 16 + lq];
#pragma unroll
      for (int r = 0; r < 4; ++r) {
        float p = __expf(T[nt][r] - mld);
        p_lds[wid][quad * 4 + r][nt * 16 + lq] = f2bf(p);
      }
    }
    // PV: O[c, e] += V[c, d] * P[d, e]
#pragma unroll
    for (int s = 0; s < 2; ++s) {
      short8 pf = *reinterpret_cast<const short8*>(
          reinterpret_cast<const unsigned char*>(&p_lds[wid][0][0]) + lq * 144 + s * 64 + quad * 16);
#pragma unroll
      for (int ct = 0; ct < 4; ++ct) {
        int row = ct * 16 + lq;
        int addr = (row * 128 + s * 64 + quad * 16) ^ ((row & 7) << 4);
        short8 vf = *reinterpret_cast<const short8*>(v_lds + addr);
        Of[ct] = __builtin_amdgcn_mfma_f32_16x16x32_bf16(vf, pf, Of[ct], 0, 0, 0);
      }
    }
  }
#pragma unroll
  for (int ct = 0; ct < 4; ++ct)
#pragma unroll
    for (int r = 0; r < 4; ++r)
      Opart[((size_t)(b * NSPLIT + split) * CO + ct * 16 + quad * 4 + r) * HW_ + e] = Of[ct][r];
}

// ---------------------------------------------------------------------------
// K4: out[f, d] = sum_c wo[f, c] * (sum_s Opart[s][c, d]) + bo[f]
// ---------------------------------------------------------------------------
__global__ __launch_bounds__(256) void outproj_kernel(
    const float* __restrict__ Opart, const float* __restrict__ wo,
    const float* __restrict__ bo, float* __restrict__ out)
{
  const int b = blockIdx.z;
  const int f0 = blockIdx.y * 32;
  const int d = blockIdx.x * 256 + threadIdx.x;
  float acc[32];
#pragma unroll
  for (int j = 0; j < 32; ++j) acc[j] = bo[f0 + j];
  const float* Ob = Opart + (size_t)b * NSPLIT * CO * HW_;
#pragma unroll 2
  for (int c = 0; c < CO; ++c) {
    float ov = Ob[(size_t)c * HW_ + d];
#pragma unroll
    for (int s = 1; s < NSPLIT; ++s) ov += Ob[(size_t)(s * CO + c) * HW_ + d];
#pragma unroll
    for (int j = 0; j < 32; ++j)
      acc[j] = fmaf(wo[(size_t)(f0 + j) * CO + c], ov, acc[j]);
  }
#pragma unroll
  for (int j = 0; j < 32; ++j)
    out[((size_t)b * CIN + f0 + j) * HW_ + d] = acc[j];
}

extern "C" void kernel_launch(void* const* d_in, const int* in_sizes, int n_in,
                              void* d_out, int out_size, void* d_ws, size_t ws_size,
                              hipStream_t stream) {
  const float* x  = (const float*)d_in[0];
  const float* wq = (const float*)d_in[1];
  const float* bq = (const float*)d_in[2];
  const float* wk = (const float*)d_in[3];
  const float* bk = (const float*)d_in[4];
  const float* wv = (const float*)d_in[5];
  const float* bv = (const float*)d_in[6];
  const float* wo = (const float*)d_in[7];
  const float* bo = (const float*)d_in[8];
  float* out = (float*)d_out;

  char* ws = (char*)d_ws;
  unsigned short* qT = (unsigned short*)(ws);                 // 2 MB  [b][4096][64] bf16
  unsigned short* kT = (unsigned short*)(ws + (2u << 20));    // 2 MB  [b][4096][64] bf16
  unsigned short* v  = (unsigned short*)(ws + (4u << 20));    // 2 MB  [b][64][4096] bf16
  float* Opart       = (float*)(ws + (6u << 20));             // 16 MB [b][4][64][4096] f32
  float* ml          = (float*)(ws + (22u << 20));            // 64 KB [b][4096] f32
  float2* parts      = (float2*)(ws + (23u << 20));           // 512KB [b][4096][4] float2

  qkv_kernel<<<dim3(64, 3, 4), 256, 0, stream>>>(x, wq, bq, wk, bk, wv, bv, qT, kT, v);
  stats_kernel<<<dim3(64, NSPLIT, 4), 256, 0, stream>>>(qT, kT, parts);
  combine_kernel<<<dim3(BB * HW_ / 256), 256, 0, stream>>>(parts, ml);
  apply_kernel<<<dim3(64, NSPLIT, 4), 256, 0, stream>>>(qT, kT, v, ml, Opart);
  outproj_kernel<<<dim3(16, 8, 4), 256, 0, stream>>>(Opart, wo, bo, out);
}

// Round 4
// 156.365 us; speedup vs baseline: 2.2413x; 1.0422x over previous
//
#include <hip/hip_runtime.h>

#define BB 4
#define CIN 256
#define CO 64
#define HW_ 4096
#define NSPLIT 8
#define DCHUNK (HW_ / NSPLIT)

typedef __attribute__((ext_vector_type(8))) short short8;
typedef __attribute__((ext_vector_type(4))) float f32x4;

__device__ inline unsigned short f2bf(float f) {
  union { float f; unsigned u; } x; x.f = f;
  unsigned r = x.u + 0x7fffu + ((x.u >> 16) & 1u);  // RNE
  return (unsigned short)(r >> 16);
}
__device__ inline float bf2f(unsigned short h) {
  union { unsigned u; float f; } x; x.u = ((unsigned)h) << 16;
  return x.f;
}

// ---------------------------------------------------------------------------
// K1: QKV projection as MFMA GEMM. One block = one of {q,k,v} x 64-pos chunk.
// ---------------------------------------------------------------------------
__global__ __launch_bounds__(256, 3) void qkv_kernel(
    const float* __restrict__ x,
    const float* __restrict__ wq, const float* __restrict__ bq,
    const float* __restrict__ wk, const float* __restrict__ bk,
    const float* __restrict__ wv, const float* __restrict__ bv,
    unsigned short* __restrict__ qT, unsigned short* __restrict__ kT,
    unsigned short* __restrict__ v)
{
  const int b = blockIdx.z;
  const int which = blockIdx.y;       // 0=q, 1=k, 2=v
  const int n0 = blockIdx.x * 64;     // position base
  const int tid = threadIdx.x;
  const int w = tid >> 6, lane = tid & 63;
  const int lq = lane & 15, quad = lane >> 4;

  const float* W  = (which == 0) ? wq : (which == 1) ? wk : wv;
  const float* Bb = (which == 0) ? bq : (which == 1) ? bk : bv;

  __shared__ unsigned short w_lds[64 * 256];   // 32 KB, [m][k] bf16 swizzled
  unsigned char* wbytes = reinterpret_cast<unsigned char*>(w_lds);

#pragma unroll
  for (int i = 0; i < 16; ++i) {
    int L = i * 256 + tid;
    int row = L >> 6, col4 = L & 63;
    float4 w4 = *reinterpret_cast<const float4*>(&W[row * 256 + col4 * 4]);
    ushort4 p;
    p.x = f2bf(w4.x); p.y = f2bf(w4.y); p.z = f2bf(w4.z); p.w = f2bf(w4.w);
    int addr = (row * 512 + col4 * 8) ^ ((row & 7) << 4);
    *reinterpret_cast<ushort4*>(wbytes + addr) = p;
  }
  __syncthreads();

  const int n = n0 + w * 16 + lq;
  const float* xb = x + (size_t)b * CIN * HW_ + n;

  const f32x4 zero = {0.f, 0.f, 0.f, 0.f};
  f32x4 acc[4];
#pragma unroll
  for (int mt = 0; mt < 4; ++mt) acc[mt] = zero;

  for (int ks = 0; ks < 8; ++ks) {
    float xv[8];
#pragma unroll
    for (int j = 0; j < 8; ++j)
      xv[j] = xb[(size_t)(ks * 32 + quad * 8 + j) * HW_];
    short8 bhi, blo;
#pragma unroll
    for (int j = 0; j < 8; ++j) {
      unsigned short h = f2bf(xv[j]);
      bhi[j] = (short)h;
      blo[j] = (short)f2bf(xv[j] - bf2f(h));
    }
#pragma unroll
    for (int mt = 0; mt < 4; ++mt) {
      int addr = ((mt * 16 + lq) * 512 + ks * 64 + quad * 16) ^ ((lq & 7) << 4);
      short8 af = *reinterpret_cast<const short8*>(wbytes + addr);
      acc[mt] = __builtin_amdgcn_mfma_f32_16x16x32_bf16(af, bhi, acc[mt], 0, 0, 0);
      acc[mt] = __builtin_amdgcn_mfma_f32_16x16x32_bf16(af, blo, acc[mt], 0, 0, 0);
    }
  }

  float4 bias4[4];
#pragma unroll
  for (int mt = 0; mt < 4; ++mt)
    bias4[mt] = *reinterpret_cast<const float4*>(&Bb[mt * 16 + quad * 4]);

  if (which < 2) {
    unsigned short* outp = ((which == 0) ? qT : kT) + ((size_t)b * HW_ + n) * 64;
#pragma unroll
    for (int mt = 0; mt < 4; ++mt) {
      ushort4 p;
      p.x = f2bf(acc[mt][0] + bias4[mt].x);
      p.y = f2bf(acc[mt][1] + bias4[mt].y);
      p.z = f2bf(acc[mt][2] + bias4[mt].z);
      p.w = f2bf(acc[mt][3] + bias4[mt].w);
      *reinterpret_cast<ushort4*>(&outp[mt * 16 + quad * 4]) = p;
    }
  } else {
#pragma unroll
    for (int mt = 0; mt < 4; ++mt) {
      float bb[4] = {bias4[mt].x, bias4[mt].y, bias4[mt].z, bias4[mt].w};
#pragma unroll
      for (int r = 0; r < 4; ++r)
        v[((size_t)b * CO + mt * 16 + quad * 4 + r) * HW_ + n] = f2bf(acc[mt][r] + bb[r]);
    }
  }
}

// ---------------------------------------------------------------------------
// K2a: partial softmax stats over an e-chunk, with next-tile prefetch.
// ---------------------------------------------------------------------------
__global__ __launch_bounds__(256, 6) void stats_kernel(
    const unsigned short* __restrict__ qT,
    const unsigned short* __restrict__ kT,
    float2* __restrict__ parts)
{
  const int b = blockIdx.z;
  const int split = blockIdx.y;
  const int dt0 = blockIdx.x * 64;
  const int tid = threadIdx.x;
  const int wid = tid >> 6, lane = tid & 63;
  const int lq = lane & 15, quad = lane >> 4;

  __shared__ unsigned char kt_lds[8192];   // [64 e][64 c] bf16, xor-swizzled

  const size_t base = (size_t)b * HW_ * CO;
  const int d = dt0 + wid * 16 + lq;
  const short8 qf0 = *reinterpret_cast<const short8*>(&qT[base + (size_t)d * 64 + quad * 8]);
  const short8 qf1 = *reinterpret_cast<const short8*>(&qT[base + (size_t)d * 64 + 32 + quad * 8]);

  float m_run = -3.0e38f, l_run = 0.f;
  const char* kT_bytes = reinterpret_cast<const char*>(kT) + base * 2;

  const int e_beg = split * DCHUNK;
  float4 kreg[2];
  auto load_k = [&](int e0) {
#pragma unroll
    for (int i = 0; i < 2; ++i) {
      int L = (i * 256 + tid) * 16;
      int row = L >> 7, colb = L & 127;
      int scol = colb ^ ((row & 7) << 4);
      kreg[i] = *reinterpret_cast<const float4*>(kT_bytes + (size_t)e0 * 128 + row * 128 + scol);
    }
  };
  load_k(e_beg);

  for (int e0 = e_beg; e0 < e_beg + DCHUNK; e0 += 64) {
    __syncthreads();
#pragma unroll
    for (int i = 0; i < 2; ++i) {
      int L = (i * 256 + tid) * 16;
      *reinterpret_cast<float4*>(kt_lds + L) = kreg[i];
    }
    __syncthreads();
    if (e0 + 64 < e_beg + DCHUNK) load_k(e0 + 64);   // prefetch next tile

    const f32x4 zero = {0.f, 0.f, 0.f, 0.f};
    f32x4 sT[4];
#pragma unroll
    for (int mt = 0; mt < 4; ++mt) sT[mt] = zero;
#pragma unroll
    for (int s = 0; s < 2; ++s)
#pragma unroll
      for (int mt = 0; mt < 4; ++mt) {
        int row = mt * 16 + lq;
        int addr = (row * 128 + s * 64 + quad * 16) ^ ((row & 7) << 4);
        short8 af = *reinterpret_cast<const short8*>(kt_lds + addr);
        sT[mt] = __builtin_amdgcn_mfma_f32_16x16x32_bf16(af, s ? qf1 : qf0, sT[mt], 0, 0, 0);
      }

    float tmax = -3.0e38f;
#pragma unroll
    for (int mt = 0; mt < 4; ++mt)
#pragma unroll
      for (int r = 0; r < 4; ++r) tmax = fmaxf(tmax, sT[mt][r]);
    tmax = fmaxf(tmax, __shfl_xor(tmax, 16));
    tmax = fmaxf(tmax, __shfl_xor(tmax, 32));
    float m_new = fmaxf(m_run, tmax);
    float corr = __expf(m_run - m_new);
    float lsum = 0.f;
#pragma unroll
    for (int mt = 0; mt < 4; ++mt)
#pragma unroll
      for (int r = 0; r < 4; ++r) lsum += __expf(sT[mt][r] - m_new);
    lsum += __shfl_xor(lsum, 16);
    lsum += __shfl_xor(lsum, 32);
    l_run = l_run * corr + lsum;
    m_run = m_new;
  }
  if (quad == 0)
    parts[((size_t)b * HW_ + d) * NSPLIT + split] = make_float2(m_run, l_run);
}

// ---------------------------------------------------------------------------
// K2b: merge per-split stats -> ml[d] = M + log sum l_i exp(m_i - M). Exact.
// ---------------------------------------------------------------------------
__global__ __launch_bounds__(256) void combine_kernel(
    const float2* __restrict__ parts, float* __restrict__ ml)
{
  const int r = blockIdx.x * 256 + threadIdx.x;
  float2 p[NSPLIT];
#pragma unroll
  for (int i = 0; i < NSPLIT; ++i) p[i] = parts[(size_t)r * NSPLIT + i];
  float M = p[0].x;
#pragma unroll
  for (int i = 1; i < NSPLIT; ++i) M = fmaxf(M, p[i].x);
  float L = 0.f;
#pragma unroll
  for (int i = 0; i < NSPLIT; ++i) L += p[i].y * __expf(p[i].x - M);
  ml[r] = M + __logf(L);
}

// ---------------------------------------------------------------------------
// K3: partial o[c,e] over a d-chunk, prefetched; bf16 NT partial stores.
// ---------------------------------------------------------------------------
__global__ __launch_bounds__(256, 6) void apply_kernel(
    const unsigned short* __restrict__ qT,
    const unsigned short* __restrict__ kT,
    const unsigned short* __restrict__ vv,
    const float* __restrict__ ml,
    unsigned short* __restrict__ Opart)
{
  const int b = blockIdx.z;
  const int split = blockIdx.y;
  const int et0 = blockIdx.x * 64;
  const int tid = threadIdx.x;
  const int wid = tid >> 6, lane = tid & 63;
  const int lq = lane & 15, quad = lane >> 4;

  __shared__ unsigned char q_lds[8192];        // [64 d][64 c] bf16, swizzled
  __shared__ unsigned char v_lds[8192];        // [64 c][64 d] bf16, swizzled
  __shared__ float ml_lds[64];
  __shared__ unsigned short p_lds[4][16][72];  // per-wave [16 e][64 d + pad]

  const size_t base = (size_t)b * HW_ * CO;
  const int e = et0 + wid * 16 + lq;
  const short8 kf0 = *reinterpret_cast<const short8*>(&kT[base + (size_t)e * 64 + quad * 8]);
  const short8 kf1 = *reinterpret_cast<const short8*>(&kT[base + (size_t)e * 64 + 32 + quad * 8]);

  const f32x4 zero = {0.f, 0.f, 0.f, 0.f};
  f32x4 Of[4];
#pragma unroll
  for (int ct = 0; ct < 4; ++ct) Of[ct] = zero;

  const char* qT_bytes = reinterpret_cast<const char*>(qT) + base * 2;
  const char* v_bytes = reinterpret_cast<const char*>(vv) + base * 2;

  const int d_beg = split * DCHUNK;
  float4 qreg[2], vreg[2];
  float mlv = 0.f;
  auto load_qv = [&](int dt) {
#pragma unroll
    for (int i = 0; i < 2; ++i) {
      int L = (i * 256 + tid) * 16;
      int row = L >> 7, colb = L & 127;
      int scol = colb ^ ((row & 7) << 4);
      qreg[i] = *reinterpret_cast<const float4*>(qT_bytes + (size_t)dt * 128 + row * 128 + scol);
      vreg[i] = *reinterpret_cast<const float4*>(v_bytes + (size_t)row * 8192 + dt * 2 + scol);
    }
    if (tid < 64) mlv = ml[(size_t)b * HW_ + dt + tid];
  };
  load_qv(d_beg);

  for (int dt = d_beg; dt < d_beg + DCHUNK; dt += 64) {
    __syncthreads();
#pragma unroll
    for (int i = 0; i < 2; ++i) {
      int L = (i * 256 + tid) * 16;
      *reinterpret_cast<float4*>(q_lds + L) = qreg[i];
      *reinterpret_cast<float4*>(v_lds + L) = vreg[i];
    }
    if (tid < 64) ml_lds[tid] = mlv;
    __syncthreads();
    if (dt + 64 < d_beg + DCHUNK) load_qv(dt + 64);   // prefetch next tile

    // T[e_loc, d_loc] = S[d, e] for wave's 16 e x 64 d
    f32x4 T[4];
#pragma unroll
    for (int nt = 0; nt < 4; ++nt) T[nt] = zero;
#pragma unroll
    for (int s = 0; s < 2; ++s)
#pragma unroll
      for (int nt = 0; nt < 4; ++nt) {
        int row = nt * 16 + lq;
        int addr = (row * 128 + s * 64 + quad * 16) ^ ((row & 7) << 4);
        short8 qfr = *reinterpret_cast<const short8*>(q_lds + addr);
        T[nt] = __builtin_amdgcn_mfma_f32_16x16x32_bf16(s ? kf1 : kf0, qfr, T[nt], 0, 0, 0);
      }
    // P = exp(S - ml[d]) -> per-wave LDS [e_loc][d_loc] bf16
#pragma unroll
    for (int nt = 0; nt < 4; ++nt) {
      float mld = ml_lds[nt * 16 + lq];
#pragma unroll
      for (int r = 0; r < 4; ++r) {
        float p = __expf(T[nt][r] - mld);
        p_lds[wid][quad * 4 + r][nt * 16 + lq] = f2bf(p);
      }
    }
    // PV: O[c, e] += V[c, d] * P[d, e]
#pragma unroll
    for (int s = 0; s < 2; ++s) {
      short8 pf = *reinterpret_cast<const short8*>(
          reinterpret_cast<const unsigned char*>(&p_lds[wid][0][0]) + lq * 144 + s * 64 + quad * 16);
#pragma unroll
      for (int ct = 0; ct < 4; ++ct) {
        int row = ct * 16 + lq;
        int addr = (row * 128 + s * 64 + quad * 16) ^ ((row & 7) << 4);
        short8 vf = *reinterpret_cast<const short8*>(v_lds + addr);
        Of[ct] = __builtin_amdgcn_mfma_f32_16x16x32_bf16(vf, pf, Of[ct], 0, 0, 0);
      }
    }
  }
#pragma unroll
  for (int ct = 0; ct < 4; ++ct)
#pragma unroll
    for (int r = 0; r < 4; ++r) {
      unsigned short hv = f2bf(Of[ct][r]);
      __builtin_nontemporal_store(hv,
          &Opart[((size_t)(b * NSPLIT + split) * CO + ct * 16 + quad * 4 + r) * HW_ + e]);
    }
}

// ---------------------------------------------------------------------------
// K4: out[f, d] = sum_c wo[f, c] * (sum_s Opart_bf16[s][c, d]) + bo[f]
// ---------------------------------------------------------------------------
__global__ __launch_bounds__(256) void outproj_kernel(
    const unsigned short* __restrict__ Opart, const float* __restrict__ wo,
    const float* __restrict__ bo, float* __restrict__ out)
{
  const int b = blockIdx.z;
  const int f0 = blockIdx.y * 32;
  const int d = blockIdx.x * 256 + threadIdx.x;
  float acc[32];
#pragma unroll
  for (int j = 0; j < 32; ++j) acc[j] = bo[f0 + j];
  const unsigned short* Ob = Opart + (size_t)b * NSPLIT * CO * HW_;
#pragma unroll 2
  for (int c = 0; c < CO; ++c) {
    float ov = 0.f;
#pragma unroll
    for (int s = 0; s < NSPLIT; ++s) ov += bf2f(Ob[(size_t)(s * CO + c) * HW_ + d]);
#pragma unroll
    for (int j = 0; j < 32; ++j)
      acc[j] = fmaf(wo[(size_t)(f0 + j) * CO + c], ov, acc[j]);
  }
#pragma unroll
  for (int j = 0; j < 32; ++j)
    out[((size_t)b * CIN + f0 + j) * HW_ + d] = acc[j];
}

extern "C" void kernel_launch(void* const* d_in, const int* in_sizes, int n_in,
                              void* d_out, int out_size, void* d_ws, size_t ws_size,
                              hipStream_t stream) {
  const float* x  = (const float*)d_in[0];
  const float* wq = (const float*)d_in[1];
  const float* bq = (const float*)d_in[2];
  const float* wk = (const float*)d_in[3];
  const float* bk = (const float*)d_in[4];
  const float* wv = (const float*)d_in[5];
  const float* bv = (const float*)d_in[6];
  const float* wo = (const float*)d_in[7];
  const float* bo = (const float*)d_in[8];
  float* out = (float*)d_out;

  char* ws = (char*)d_ws;
  unsigned short* qT    = (unsigned short*)(ws);               // 2 MB  [b][4096][64] bf16
  unsigned short* kT    = (unsigned short*)(ws + (2u << 20));  // 2 MB  [b][4096][64] bf16
  unsigned short* v     = (unsigned short*)(ws + (4u << 20));  // 2 MB  [b][64][4096] bf16
  unsigned short* Opart = (unsigned short*)(ws + (6u << 20));  // 16 MB [b][8][64][4096] bf16
  float* ml             = (float*)(ws + (23u << 20));          // 64 KB [b][4096] f32
  float2* parts         = (float2*)(ws + (24u << 20));         // 1 MB  [b][4096][8] float2

  qkv_kernel<<<dim3(64, 3, 4), 256, 0, stream>>>(x, wq, bq, wk, bk, wv, bv, qT, kT, v);
  stats_kernel<<<dim3(64, NSPLIT, 4), 256, 0, stream>>>(qT, kT, parts);
  combine_kernel<<<dim3(BB * HW_ / 256), 256, 0, stream>>>(parts, ml);
  apply_kernel<<<dim3(64, NSPLIT, 4), 256, 0, stream>>>(qT, kT, v, ml, Opart);
  outproj_kernel<<<dim3(16, 8, 4), 256, 0, stream>>>(Opart, wo, bo, out);
}